// Round 6
// baseline (324.874 us; speedup 1.0000x reference)
//
#include <hip/hip_runtime.h>
#include <hip/hip_bf16.h>
#include <hip/hip_fp8.h>

#define O_NODES 50000
#define N_EDGES 200000
#define DD 256
#define S_SLOTS 32
#define OVF_CAP 4096

typedef float f32x4 __attribute__((ext_vector_type(4)));

// ---------- fp8 e4m3 helpers ----------
__device__ __forceinline__ unsigned pack4_fp8(float a, float b, float c, float d) {
#if __has_builtin(__builtin_amdgcn_cvt_pk_fp8_f32)
    int v = __builtin_amdgcn_cvt_pk_fp8_f32(a, b, 0, false);
    v = __builtin_amdgcn_cvt_pk_fp8_f32(c, d, v, true);
    return (unsigned)v;
#else
    __hip_fp8_e4m3 x(a), y(b), z(c), w(d);
    return (unsigned)x.__x | ((unsigned)y.__x << 8) | ((unsigned)z.__x << 16) | ((unsigned)w.__x << 24);
#endif
}

__device__ __forceinline__ unsigned char f2fp8(float x) {
#if __has_builtin(__builtin_amdgcn_cvt_pk_fp8_f32)
    return (unsigned char)(__builtin_amdgcn_cvt_pk_fp8_f32(x, x, 0, false) & 0xff);
#else
    __hip_fp8_e4m3 t(x); return t.__x;
#endif
}

__device__ __forceinline__ f32x4 unpack4_fp8(unsigned v) {
#if __has_builtin(__builtin_amdgcn_cvt_pk_f32_fp8)
    auto lo = __builtin_amdgcn_cvt_pk_f32_fp8((int)v, false);
    auto hi = __builtin_amdgcn_cvt_pk_f32_fp8((int)v, true);
    return (f32x4){lo[0], lo[1], hi[0], hi[1]};
#else
    __hip_fp8_e4m3 t0, t1, t2, t3;
    t0.__x = v & 0xff; t1.__x = (v >> 8) & 0xff; t2.__x = (v >> 16) & 0xff; t3.__x = (v >> 24) & 0xff;
    return (f32x4){(float)t0, (float)t1, (float)t2, (float)t3};
#endif
}

__device__ __forceinline__ f32x4 mfma_fp8(long a, long b, f32x4 c) {
    return __builtin_amdgcn_mfma_f32_16x16x32_fp8_fp8(a, b, c, 0, 0, 0);
}

// ---------- generic input helpers ----------
__device__ __forceinline__ int get_pair(const int* __restrict__ p, long e, int which, int is32) {
    return is32 ? p[2 * e + which] : p[4 * e + 2 * which];
}

__device__ __forceinline__ float load_f(const void* p, long i, int is_f32) {
    if (is_f32) return ((const float*)p)[i];
    unsigned short u = ((const unsigned short*)p)[i];
    return __uint_as_float((unsigned)u << 16);
}

__device__ __forceinline__ float bf2f(unsigned short u) {
    return __uint_as_float((unsigned)u << 16);
}

__device__ __forceinline__ unsigned short f2bf(float x) {
    __hip_bfloat16 h = __float2bfloat16(x);
    return *(unsigned short*)&h;
}

// wave-collective dtype probes (call with full wave active, before any divergence)
__device__ __forceinline__ int detect_is32_w(const int* __restrict__ pairs) {
    int lane = threadIdx.x & 63;
    unsigned long long m = __ballot(pairs[2 * lane + 1] != 0);  // int64 high words all 0
    return m != 0ull;
}
__device__ __forceinline__ int detect_isf_w(const unsigned short* __restrict__ w) {
    int lane = threadIdx.x & 63;
    unsigned short u = w[2 * lane];
    float v = fabsf(__uint_as_float((unsigned)u << 16));
    unsigned long long m = __ballot(v > 0.004f && v < 16.0f);
    return (__popcll(m) < 32) ? 1 : 0;   // low halves mostly out-of-range => f32
}

// ---------- mega setup: pack W1cat+W2cat | edge max+count+slot write | bconv | flag ----------
#define MEGA_B 2048
#define MEGA_C 782
__global__ __launch_bounds__(256) void mega_setup(
    const void* __restrict__ objf, const int* __restrict__ pairs, const void* __restrict__ conf,
    const void* __restrict__ W1, const void* __restrict__ W2,
    const void* __restrict__ b1, const void* __restrict__ b2,
    unsigned char* __restrict__ w1p, unsigned char* __restrict__ w2p,
    float* __restrict__ b1f, float* __restrict__ b2f,
    float* __restrict__ mbuf, int* __restrict__ count, int* __restrict__ flag,
    int2* __restrict__ inc2, int4* __restrict__ ovf)
{
    int b = blockIdx.x, t = threadIdx.x;
    if (b < MEGA_B) {
        int isf = detect_isf_w((const unsigned short*)objf);
        int idx = ((b & 1023) << 8) + t;
        if (b < 1024) {    // W1cat [256][1024], N-concat
            int j = idx & 7, half = (idx >> 3) & 1, lane = (idx >> 4) & 63;
            int p = (idx >> 10) & 31, tk = idx >> 15;
            int k = tk * 32 + (lane >> 4) * 8 + j;
            int n = (2 * p + half) * 16 + (lane & 15);
            long src = (n < 512) ? ((long)k * 512 + n) : ((long)(256 + k) * 512 + (n - 512));
            w1p[idx] = f2fp8(load_f(W1, src, isf));
        } else {           // W2cat [1024][256], K-concat
            int j = idx & 7, half = (idx >> 3) & 1, lane = (idx >> 4) & 63;
            int p = (idx >> 10) & 7, tk = idx >> 13;
            int k = tk * 32 + (lane >> 4) * 8 + j;
            int n = (2 * p + half) * 16 + (lane & 15);
            long src = (k < 512) ? ((long)k * 512 + n) : ((long)(k - 512) * 512 + 256 + n);
            w2p[idx] = f2fp8(load_f(W2, src, isf));
        }
    } else if (b < MEGA_B + MEGA_C) {
        int is32 = detect_is32_w(pairs);
        int isf  = detect_isf_w((const unsigned short*)objf);
        int i = (b - MEGA_B) * 256 + t;
        if (i >= N_EDGES) return;
        int s = get_pair(pairs, i, 0, is32);
        int o = get_pair(pairs, i, 1, is32);
        float c = load_f(conf, i, isf);
        c = fminf(fmaxf(c, -80.f), 80.f);        // keep exp finite; identity for |c|<=80
        int cb = __float_as_int(c);
        int eb = __float_as_int(__expf(c));      // records carry exp(conf); w = expc*exp(-mm)
        // mbuf memset 0; mbuf = max(0, max conf) — shift point arbitrary, rescaled exactly
        // by S = exp(mbuf - max(mbuf,10)) in the gemm2 epilogue.
        atomicMax((int*)&mbuf[s], cb);
        atomicMax((int*)&mbuf[o], cb);
        int idx_s = atomicAdd(&count[s], 1);
        int rec_s = (o << 1) | 0;                // s is SUB of edge i
        if (idx_s < S_SLOTS) inc2[(long)s * S_SLOTS + idx_s] = make_int2(rec_s, eb);
        else { int oi = atomicAdd(&flag[2], 1); if (oi < OVF_CAP) ovf[oi] = make_int4(s, rec_s, eb, 0); }
        int idx_o = atomicAdd(&count[o], 1);
        int rec_o = (s << 1) | 1;                // o is OBJ of edge i
        if (idx_o < S_SLOTS) inc2[(long)o * S_SLOTS + idx_o] = make_int2(rec_o, eb);
        else { int oi = atomicAdd(&flag[2], 1); if (oi < OVF_CAP) ovf[oi] = make_int4(o, rec_o, eb, 0); }
    } else if (b == MEGA_B + MEGA_C) {
        int isf = detect_isf_w((const unsigned short*)objf);
        b1f[t]       = load_f(b1, t, isf);
        b1f[256 + t] = load_f(b1, 256 + t, isf);
        b2f[t]       = load_f(b2, t, isf);
        b2f[256 + t] = load_f(b2, 256 + t, isf);
    } else {
        int is32 = detect_is32_w(pairs);
        int isf  = detect_isf_w((const unsigned short*)objf);
        if (t == 0) { flag[0] = is32; flag[1] = isf; }
    }
}

// ---------- node-level GEMM1: P[50k][1024] fp8 = cvt_fp8(objf) @ W1cat[256][1024] ----------
__global__ __launch_bounds__(512, 4) void gemm1_node(
    const void* __restrict__ objf,
    const unsigned char* __restrict__ w1p,
    unsigned char* __restrict__ P)
{
    extern __shared__ char smem[];
    unsigned char* sA = (unsigned char*)smem;    // frag: 16KB; epi: 64x528 = 33792

    const int isf = detect_isf_w((const unsigned short*)objf);

    const int tid  = threadIdx.x;
    const int wave = tid >> 6;
    const int lane = tid & 63;
    const int l15  = lane & 15;
    const int lq   = lane >> 4;
    const int mb   = blockIdx.x >> 1;
    const int nh   = blockIdx.x & 1;
    const long bs  = (long)mb * 64;

    // stage A: 64 rows x 32 k-octets = 2048 uint2; 4 per thread, cvt->fp8, frag-major dest
    #pragma unroll
    for (int it = 0; it < 4; ++it) {
        int q   = it * 512 + tid;
        int m15 = q & 15;
        int mtp = (q >> 4) & 1;
        int h   = (q >> 5) & 1;
        int lqk = (q >> 6) & 3;
        int tk  = (q >> 8) & 7;
        int m   = (h * 2 + mtp) * 16 + m15;
        long node = bs + m; if (node >= O_NODES) node = O_NODES - 1;
        long f4 = node * 64 + tk * 8 + lqk * 2;   // float4/ushort4 index (4 values each)
        uint2 v;
        if (isf) {
            float4 a = ((const float4*)objf)[f4];
            float4 c = ((const float4*)objf)[f4 + 1];
            v.x = pack4_fp8(a.x, a.y, a.z, a.w);
            v.y = pack4_fp8(c.x, c.y, c.z, c.w);
        } else {
            ushort4 a = ((const ushort4*)objf)[f4];
            ushort4 c = ((const ushort4*)objf)[f4 + 1];
            v.x = pack4_fp8(bf2f(a.x), bf2f(a.y), bf2f(a.z), bf2f(a.w));
            v.y = pack4_fp8(bf2f(c.x), bf2f(c.y), bf2f(c.z), bf2f(c.w));
        }
        *(uint2*)(sA + h * 8192 + (tk * 64 + lqk * 16 + m15) * 16 + mtp * 8) = v;
    }
    __syncthreads();

    f32x4 acc[4][4];
    #pragma unroll
    for (int mt = 0; mt < 4; ++mt)
        #pragma unroll
        for (int nt = 0; nt < 4; ++nt)
            acc[mt][nt] = (f32x4){0.f, 0.f, 0.f, 0.f};

    {
        const ulonglong2* bq = (const ulonglong2*)w1p;
        const int pbase = nh * 16 + wave * 2;
        #pragma unroll 2
        for (int tk = 0; tk < 8; ++tk) {
            ulonglong2 av01 = *(const ulonglong2*)(sA + tk * 1024 + lane * 16);
            ulonglong2 av23 = *(const ulonglong2*)(sA + 8192 + tk * 1024 + lane * 16);
            ulonglong2 b01  = bq[(tk * 32 + pbase) * 64 + lane];
            ulonglong2 b23  = bq[(tk * 32 + pbase + 1) * 64 + lane];
            long a0 = (long)av01.x, a1 = (long)av01.y;
            long a2 = (long)av23.x, a3 = (long)av23.y;
            acc[0][0] = mfma_fp8(a0, (long)b01.x, acc[0][0]);
            acc[1][0] = mfma_fp8(a1, (long)b01.x, acc[1][0]);
            acc[2][0] = mfma_fp8(a2, (long)b01.x, acc[2][0]);
            acc[3][0] = mfma_fp8(a3, (long)b01.x, acc[3][0]);
            acc[0][1] = mfma_fp8(a0, (long)b01.y, acc[0][1]);
            acc[1][1] = mfma_fp8(a1, (long)b01.y, acc[1][1]);
            acc[2][1] = mfma_fp8(a2, (long)b01.y, acc[2][1]);
            acc[3][1] = mfma_fp8(a3, (long)b01.y, acc[3][1]);
            acc[0][2] = mfma_fp8(a0, (long)b23.x, acc[0][2]);
            acc[1][2] = mfma_fp8(a1, (long)b23.x, acc[1][2]);
            acc[2][2] = mfma_fp8(a2, (long)b23.x, acc[2][2]);
            acc[3][2] = mfma_fp8(a3, (long)b23.x, acc[3][2]);
            acc[0][3] = mfma_fp8(a0, (long)b23.y, acc[0][3]);
            acc[1][3] = mfma_fp8(a1, (long)b23.y, acc[1][3]);
            acc[2][3] = mfma_fp8(a2, (long)b23.y, acc[2][3]);
            acc[3][3] = mfma_fp8(a3, (long)b23.y, acc[3][3]);
        }
    }
    __syncthreads();

    // fp8 row-major (stride 528) -> coalesced stream into P
    #pragma unroll
    for (int nt = 0; nt < 4; ++nt) {
        int c = wave * 64 + nt * 16 + l15;
        #pragma unroll
        for (int mt = 0; mt < 4; ++mt) {
            #pragma unroll
            for (int r = 0; r < 4; ++r) {
                sA[(mt * 16 + lq * 4 + r) * 528 + c] = f2fp8(acc[mt][nt][r]);
            }
        }
    }
    __syncthreads();
    #pragma unroll
    for (int it = 0; it < 4; ++it) {
        int idx = it * 512 + tid;
        int row = idx >> 5;
        int ch  = idx & 31;
        if (bs + row < O_NODES) {
            uint4 v = *(const uint4*)(sA + row * 528 + ch * 16);
            ((uint4*)P)[(bs + row) * 64 + nh * 32 + ch] = v;
        }
    }
}

// ---------- per-node weighted-h accumulation ----------
// 2 waves/node-slice (256-dim halves), 8 nodes serial per wave, 2-deep software pipeline:
// node t+2's records/meta/self and node t+1's first partner batch issue during node t's ACC.
// All batches are masked full-8 (no serial tail): k>=kb lanes read slot-0's partner (valid,
// finite fp8) with weight selected to exact 0.0f.
__global__ __launch_bounds__(256) void node_accum(
    const unsigned* __restrict__ Pu,     // P as uints, row = 256 uints
    const int2* __restrict__ inc2,       // [50000][32] {partner<<1|role, exp(conf) bits}
    const int* __restrict__ count,
    const float* __restrict__ mbuf,
    const int* __restrict__ flag,        // flag[2] = overflow count
    const int4* __restrict__ ovf,
    const float4* __restrict__ b1f4,
    unsigned* __restrict__ Hcat_u,       // row = 256 uints: [Hs 128 | Ho 128]
    float* __restrict__ ws_s, float* __restrict__ ws_o)
{
    const int lane = threadIdx.x & 63;
    const int hw   = (threadIdx.x >> 6) & 1;             // 256-dim half owned by this wave
    const int nbase = __builtin_amdgcn_readfirstlane(
        (blockIdx.x * 2 + (threadIdx.x >> 7)) * 8);      // 3125 blocks * 2 slices * 8 = 50000
    const int col  = hw * 64 + lane;

    float4 bqv = b1f4[col];
    f32x4 b1v = {bqv.x, bqv.y, bqv.z, bqv.w};

    // ---- pipeline stage A (node t): records+meta+self+partner batch0
    //      stage B (node t+1): records+meta+self
    int4 a0, a1, a2, a3; int degA; float mmA; unsigned stA, sbA; unsigned pvA[8];
    int4 c0, c1, c2, c3; int degB; float mmB; unsigned stB, sbB;

    {   // load A = node nbase
        const int4* s = (const int4*)(inc2 + (long)nbase * S_SLOTS);
        a0 = s[0]; a1 = s[1]; a2 = s[2]; a3 = s[3];
        degA = count[nbase]; mmA = mbuf[nbase];
        stA = Pu[(long)nbase * 256 + col]; sbA = Pu[(long)nbase * 256 + 128 + col];
    }
    {   // issue A partner batch0 (masked full 8)
        int kb = degA < 8 ? degA : 8;
        int rx[8] = {a0.x, a0.z, a1.x, a1.z, a2.x, a2.z, a3.x, a3.z};
        #pragma unroll
        for (int k = 0; k < 8; ++k) {
            int r = (k < kb) ? rx[k] : (kb ? rx[0] : 0);
            pvA[k] = Pu[(long)(r >> 1) * 256 + ((r & 1) ? 0 : 128) + col];
        }
    }
    {   // load B = node nbase+1
        const int4* s = (const int4*)(inc2 + (long)(nbase + 1) * S_SLOTS);
        c0 = s[0]; c1 = s[1]; c2 = s[2]; c3 = s[3];
        degB = count[nbase + 1]; mmB = mbuf[nbase + 1];
        stB = Pu[(long)(nbase + 1) * 256 + col]; sbB = Pu[(long)(nbase + 1) * 256 + 128 + col];
    }

    #pragma unroll 1
    for (int t = 0; t < 8; ++t) {
        const int n = nbase + t;
        // issue stage C = node t+2 (records+meta+self)
        int4 n0 = {0,0,0,0}, n1 = {0,0,0,0}, n2 = {0,0,0,0}, n3 = {0,0,0,0};
        int degC = 0; float mmC = 0.f; unsigned stC = 0, sbC = 0;
        if (t < 6) {
            const int4* s = (const int4*)(inc2 + (long)(n + 2) * S_SLOTS);
            n0 = s[0]; n1 = s[1]; n2 = s[2]; n3 = s[3];
            degC = count[n + 2]; mmC = mbuf[n + 2];
            stC = Pu[(long)(n + 2) * 256 + col]; sbC = Pu[(long)(n + 2) * 256 + 128 + col];
        }
        // issue node t+1's partner batch0 (masked full 8)
        unsigned pvB[8];
        if (t < 7) {
            int kb = degB < 8 ? degB : 8;
            int rx[8] = {c0.x, c0.z, c1.x, c1.z, c2.x, c2.z, c3.x, c3.z};
            #pragma unroll
            for (int k = 0; k < 8; ++k) {
                int r = (k < kb) ? rx[k] : (kb ? rx[0] : 0);
                pvB[k] = Pu[(long)(r >> 1) * 256 + ((r & 1) ? 0 : 128) + col];
            }
        }

        // ---- process node A ----
        const float emm = __expf(-mmA);
        f32x4 ots = unpack4_fp8(stA), obs = unpack4_fp8(sbA);
        f32x4 otb, obb;
        #pragma unroll
        for (int j = 0; j < 4; ++j) { otb[j] = ots[j] + b1v[j]; obb[j] = obs[j] + b1v[j]; }

        f32x4 accS = {0.f, 0.f, 0.f, 0.f}, accO = {0.f, 0.f, 0.f, 0.f};
        float wS = 0.f, wO = 0.f;

        auto ACC1 = [&](int r, float wk, unsigned pv) {
            f32x4 pp = unpack4_fp8(pv);
            if (r & 1) {         // wave-uniform: n is OBJ of this edge
                wO += wk;
                #pragma unroll
                for (int j = 0; j < 4; ++j) accO[j] += wk * fmaxf(obb[j] + pp[j], 0.f);
            } else {             // n is SUB
                wS += wk;
                #pragma unroll
                for (int j = 0; j < 4; ++j) accS[j] += wk * fmaxf(otb[j] + pp[j], 0.f);
            }
        };

        {   // batch0 from prefetched pvA
            int kb = degA < 8 ? degA : 8;
            int rx[8] = {a0.x, a0.z, a1.x, a1.z, a2.x, a2.z, a3.x, a3.z};
            int ry[8] = {a0.y, a0.w, a1.y, a1.w, a2.y, a2.w, a3.y, a3.w};
            #pragma unroll
            for (int k = 0; k < 8; ++k) {
                int r = (k < kb) ? rx[k] : (kb ? rx[0] : 0);
                float wk = (k < kb) ? __int_as_float(ry[k]) * emm : 0.f;
                ACC1(r, wk, pvA[k]);
            }
        }
        // extra batches (deg>8), masked full-8, loads grouped before use
        const int nb = degA < S_SLOTS ? degA : S_SLOTS;
        for (int i = 8; i < nb; i += 8) {
            const int4* s = (const int4*)(inc2 + (long)n * S_SLOTS + i);
            int4 q0 = s[0], q1 = s[1], q2 = s[2], q3 = s[3];
            int kb = (nb - i) < 8 ? (nb - i) : 8;
            int rx[8] = {q0.x, q0.z, q1.x, q1.z, q2.x, q2.z, q3.x, q3.z};
            int ry[8] = {q0.y, q0.w, q1.y, q1.w, q2.y, q2.w, q3.y, q3.w};
            unsigned pv[8];
            #pragma unroll
            for (int k = 0; k < 8; ++k) {
                int r = (k < kb) ? rx[k] : rx[0];   // kb >= 1 here
                pv[k] = Pu[(long)(r >> 1) * 256 + ((r & 1) ? 0 : 128) + col];
            }
            #pragma unroll
            for (int k = 0; k < 8; ++k) {
                int r = (k < kb) ? rx[k] : rx[0];
                float wk = (k < kb) ? __int_as_float(ry[k]) * emm : 0.f;
                ACC1(r, wk, pv[k]);
            }
        }
        if (degA > S_SLOTS) {   // rare overflow: walk the global overflow list
            int no = flag[2]; if (no > OVF_CAP) no = OVF_CAP;
            for (int tt = 0; tt < no; ++tt) {
                int4 o = ovf[tt];
                if (o.x == n) {
                    unsigned pv = Pu[(long)(o.y >> 1) * 256 + ((o.y & 1) ? 0 : 128) + col];
                    ACC1(o.y, __int_as_float(o.z) * emm, pv);
                }
            }
        }
        long hrow = (long)n * 256;
        Hcat_u[hrow + col]       = pack4_fp8(accS[0], accS[1], accS[2], accS[3]);
        Hcat_u[hrow + 128 + col] = pack4_fp8(accO[0], accO[1], accO[2], accO[3]);
        if (hw == 0 && lane == 0) { ws_s[n] = wS; ws_o[n] = wO; }

        // rotate pipeline: A <= B, B <= C
        a0 = c0; a1 = c1; a2 = c2; a3 = c3;
        degA = degB; mmA = mmB; stA = stB; sbA = sbB;
        #pragma unroll
        for (int k = 0; k < 8; ++k) pvA[k] = pvB[k];
        c0 = n0; c1 = n1; c2 = n2; c3 = n3;
        degB = degC; mmB = mmC; stB = stC; sbB = sbC;
    }
}

// ---------- node-level GEMM2 + fused finalize ----------
__global__ __launch_bounds__(512, 4) void gemm2_node(
    const unsigned* __restrict__ Hcat,
    const unsigned char* __restrict__ w2p,
    const float* __restrict__ mbuf,
    const float* __restrict__ ws_s, const float* __restrict__ ws_o,
    const void* __restrict__ objf, const float* __restrict__ b2f,
    void* __restrict__ out, const int* __restrict__ flag)
{
    extern __shared__ char smem[];
    unsigned char* sA = (unsigned char*)smem;     // 32KB frags
    float* sS    = (float*)(smem + 32768);        // [64] each
    float* sSelf = sS + 64;
    float* sInv  = sS + 128;
    float* sWs   = sS + 192;
    float* sWo   = sS + 256;

    const int tid  = threadIdx.x;
    const int wave = tid >> 6;
    const int lane = tid & 63;
    const int l15  = lane & 15;
    const int lq   = lane >> 4;
    const long bs  = (long)blockIdx.x * 64;
    const int isf  = flag[1];

    if (tid < 64) {
        long node = bs + tid; if (node >= O_NODES) node = O_NODES - 1;
        float mm = mbuf[node];
        float mn = fmaxf(mm, 10.0f);
        float S     = __expf(mm - mn);
        float selfw = __expf(10.0f - mn);
        float wss = ws_s[node], wso = ws_o[node];
        sS[tid] = S; sSelf[tid] = selfw; sWs[tid] = wss; sWo[tid] = wso;
        sInv[tid] = 1.0f / (S * (wss + wso) + selfw);
    }

    f32x4 acc[4][2];
    #pragma unroll
    for (int mt = 0; mt < 4; ++mt)
        #pragma unroll
        for (int nt = 0; nt < 2; ++nt)
            acc[mt][nt] = (f32x4){0.f, 0.f, 0.f, 0.f};

    const ulonglong2* bq = (const ulonglong2*)w2p;
    #pragma unroll
    for (int kh = 0; kh < 2; ++kh) {
        #pragma unroll
        for (int it = 0; it < 8; ++it) {
            int q   = it * 512 + tid;
            int m15 = q & 15;
            int mtp = (q >> 4) & 1;
            int h   = (q >> 5) & 1;
            int lqk = (q >> 6) & 3;
            int tk  = (q >> 8) & 15;
            int m   = (h * 2 + mtp) * 16 + m15;
            long node = bs + m; if (node >= O_NODES) node = O_NODES - 1;
            uint2 v = *(const uint2*)(Hcat + node * 256 + kh * 128 + tk * 8 + lqk * 2);
            *(uint2*)(sA + h * 16384 + (tk * 64 + lqk * 16 + m15) * 16 + mtp * 8) = v;
        }
        __syncthreads();
        #pragma unroll 2
        for (int tk = 0; tk < 16; ++tk) {
            int kt = kh * 16 + tk;
            ulonglong2 av01 = *(const ulonglong2*)(sA + tk * 1024 + lane * 16);
            ulonglong2 av23 = *(const ulonglong2*)(sA + 16384 + tk * 1024 + lane * 16);
            ulonglong2 b    = bq[(kt * 8 + wave) * 64 + lane];
            long a0 = (long)av01.x, a1 = (long)av01.y;
            long a2 = (long)av23.x, a3 = (long)av23.y;
            acc[0][0] = mfma_fp8(a0, (long)b.x, acc[0][0]);
            acc[1][0] = mfma_fp8(a1, (long)b.x, acc[1][0]);
            acc[2][0] = mfma_fp8(a2, (long)b.x, acc[2][0]);
            acc[3][0] = mfma_fp8(a3, (long)b.x, acc[3][0]);
            acc[0][1] = mfma_fp8(a0, (long)b.y, acc[0][1]);
            acc[1][1] = mfma_fp8(a1, (long)b.y, acc[1][1]);
            acc[2][1] = mfma_fp8(a2, (long)b.y, acc[2][1]);
            acc[3][1] = mfma_fp8(a3, (long)b.y, acc[3][1]);
        }
        __syncthreads();
    }

    // fused finalize epilogue
    #pragma unroll
    for (int nt = 0; nt < 2; ++nt) {
        int c = wave * 32 + nt * 16 + l15;
        float b2c = b2f[c];
        float b2d = b2f[256 + c];
        #pragma unroll
        for (int mt = 0; mt < 4; ++mt) {
            #pragma unroll
            for (int r = 0; r < 4; ++r) {
                int row = mt * 16 + lq * 4 + r;
                long node = bs + row;
                if (node < O_NODES) {
                    float o = load_f(objf, node * 256 + c, isf);
                    float val = (sS[row] * (acc[mt][nt][r] + sWs[row] * b2c + sWo[row] * b2d)
                                 + sSelf[row] * o) * sInv[row];
                    if (isf) ((float*)out)[node * 256 + c] = val;
                    else     ((unsigned short*)out)[node * 256 + c] = f2bf(val);
                }
            }
        }
    }
}

extern "C" void kernel_launch(void* const* d_in, const int* in_sizes, int n_in,
                              void* d_out, int out_size, void* d_ws, size_t ws_size,
                              hipStream_t stream) {
    const void* objf  = d_in[0];
    const int*  pairs = (const int*)d_in[1];
    const void* conf  = d_in[2];
    const void* W1    = d_in[3];
    const void* b1    = d_in[4];
    const void* W2    = d_in[5];
    const void* b2    = d_in[6];

    char* ws = (char*)d_ws;
    // layout (bytes):
    //   0         count   200000
    //   200000    mbuf    200000
    //   400000    flag    64       (flag[2] = overflow counter)
    //   400064    ovf     65536    (int4 x 4096)
    //   465600    w1p     262144
    //   727744    w2p     262144
    //   989888    ws_s    200000
    //   1189888   ws_o    200000
    //   1389888   b1f     2048
    //   1391936   b2f     2048
    //   1393984   inc2    12800000 (int2 slots [50000][32])
    //   14193984  P       51200000 (fp8 [50k][1024])
    //   65393984  Hcat    51200000
    //   end = 116,593,984  (< 118,124,352 proven available)
    int*   count   = (int*)  ws;
    float* mbuf    = (float*)(ws + 200000);
    int*   flag    = (int*)  (ws + 400000);
    int4*  ovf     = (int4*) (ws + 400064);
    unsigned char* w1p = (unsigned char*)(ws + 465600);
    unsigned char* w2p = (unsigned char*)(ws + 727744);
    float* wss     = (float*)(ws + 989888);
    float* wso     = (float*)(ws + 1189888);
    float* b1f     = (float*)(ws + 1389888);
    float* b2f     = (float*)(ws + 1391936);
    int2*  inc2    = (int2*) (ws + 1393984);
    unsigned char* P     = (unsigned char*)(ws + 14193984);
    unsigned char* Hcat  = (unsigned char*)(ws + 65393984);

    hipMemsetAsync(count, 0, 400064, stream);   // count + mbuf(0) + flag(incl. ovf counter)

    mega_setup<<<MEGA_B + MEGA_C + 2, 256, 0, stream>>>(
        objf, pairs, conf, W1, W2, b1, b2, w1p, w2p, b1f, b2f,
        mbuf, count, flag, inc2, ovf);

    gemm1_node<<<2 * ((O_NODES + 63) / 64), 512, 33792, stream>>>(objf, w1p, P);

    node_accum<<<O_NODES / 16, 256, 0, stream>>>(
        (const unsigned*)P, inc2, count, mbuf, flag, ovf, (const float4*)b1f,
        (unsigned*)Hcat, wss, wso);

    gemm2_node<<<(O_NODES + 63) / 64, 512, 34048, stream>>>(
        (const unsigned*)Hcat, w2p, mbuf, wss, wso, objf, b2f, d_out, flag);
}

// Round 7
// 294.238 us; speedup vs baseline: 1.1041x; 1.1041x over previous
//
#include <hip/hip_runtime.h>
#include <hip/hip_bf16.h>
#include <hip/hip_fp8.h>

#define O_NODES 50000
#define N_EDGES 200000
#define DD 256
#define S_SLOTS 32
#define OVF_CAP 4096

typedef float f32x4 __attribute__((ext_vector_type(4)));

// ---------- fp8 e4m3 helpers ----------
__device__ __forceinline__ unsigned pack4_fp8(float a, float b, float c, float d) {
#if __has_builtin(__builtin_amdgcn_cvt_pk_fp8_f32)
    int v = __builtin_amdgcn_cvt_pk_fp8_f32(a, b, 0, false);
    v = __builtin_amdgcn_cvt_pk_fp8_f32(c, d, v, true);
    return (unsigned)v;
#else
    __hip_fp8_e4m3 x(a), y(b), z(c), w(d);
    return (unsigned)x.__x | ((unsigned)y.__x << 8) | ((unsigned)z.__x << 16) | ((unsigned)w.__x << 24);
#endif
}

__device__ __forceinline__ unsigned char f2fp8(float x) {
#if __has_builtin(__builtin_amdgcn_cvt_pk_fp8_f32)
    return (unsigned char)(__builtin_amdgcn_cvt_pk_fp8_f32(x, x, 0, false) & 0xff);
#else
    __hip_fp8_e4m3 t(x); return t.__x;
#endif
}

__device__ __forceinline__ f32x4 unpack4_fp8(unsigned v) {
#if __has_builtin(__builtin_amdgcn_cvt_pk_f32_fp8)
    auto lo = __builtin_amdgcn_cvt_pk_f32_fp8((int)v, false);
    auto hi = __builtin_amdgcn_cvt_pk_f32_fp8((int)v, true);
    return (f32x4){lo[0], lo[1], hi[0], hi[1]};
#else
    __hip_fp8_e4m3 t0, t1, t2, t3;
    t0.__x = v & 0xff; t1.__x = (v >> 8) & 0xff; t2.__x = (v >> 16) & 0xff; t3.__x = (v >> 24) & 0xff;
    return (f32x4){(float)t0, (float)t1, (float)t2, (float)t3};
#endif
}

__device__ __forceinline__ f32x4 mfma_fp8(long a, long b, f32x4 c) {
    return __builtin_amdgcn_mfma_f32_16x16x32_fp8_fp8(a, b, c, 0, 0, 0);
}

// ---------- generic input helpers ----------
__device__ __forceinline__ int get_pair(const int* __restrict__ p, long e, int which, int is32) {
    return is32 ? p[2 * e + which] : p[4 * e + 2 * which];
}

__device__ __forceinline__ float load_f(const void* p, long i, int is_f32) {
    if (is_f32) return ((const float*)p)[i];
    unsigned short u = ((const unsigned short*)p)[i];
    return __uint_as_float((unsigned)u << 16);
}

__device__ __forceinline__ float bf2f(unsigned short u) {
    return __uint_as_float((unsigned)u << 16);
}

__device__ __forceinline__ unsigned short f2bf(float x) {
    __hip_bfloat16 h = __float2bfloat16(x);
    return *(unsigned short*)&h;
}

// wave-collective dtype probes (call with full wave active, before any divergence)
__device__ __forceinline__ int detect_is32_w(const int* __restrict__ pairs) {
    int lane = threadIdx.x & 63;
    unsigned long long m = __ballot(pairs[2 * lane + 1] != 0);  // int64 high words all 0
    return m != 0ull;
}
__device__ __forceinline__ int detect_isf_w(const unsigned short* __restrict__ w) {
    int lane = threadIdx.x & 63;
    unsigned short u = w[2 * lane];
    float v = fabsf(__uint_as_float((unsigned)u << 16));
    unsigned long long m = __ballot(v > 0.004f && v < 16.0f);
    return (__popcll(m) < 32) ? 1 : 0;   // low halves mostly out-of-range => f32
}

// ---------- K1: zero count/mbuf/flag | W1cat pack | bias conv | flag ----------
// W1cat pack, fp8, [K=256][N=1024], N-concat (mapping depends only on linear idx).
#define Z_BLK 49
#define W1_BLK 512
__global__ __launch_bounds__(512) void setup1(
    const void* __restrict__ objf, const int* __restrict__ pairs,
    const void* __restrict__ W1, const void* __restrict__ b1, const void* __restrict__ b2,
    unsigned char* __restrict__ w1p, float* __restrict__ b1f, float* __restrict__ b2f,
    char* __restrict__ zbase, int* __restrict__ flag)
{
    int b = blockIdx.x, t = threadIdx.x;
    if (b < Z_BLK) {                       // zero 400064 B (count+mbuf+flag) as int4
        int idx = b * 512 + t;
        if (idx < 25004) ((int4*)zbase)[idx] = make_int4(0, 0, 0, 0);
    } else if (b < Z_BLK + W1_BLK) {       // W1cat pack
        int isf = detect_isf_w((const unsigned short*)objf);
        int idx = (b - Z_BLK) * 512 + t;   // 0..262143
        int j = idx & 7, half = (idx >> 3) & 1, lane = (idx >> 4) & 63;
        int p = (idx >> 10) & 31, tk = idx >> 15;
        int k = tk * 32 + (lane >> 4) * 8 + j;
        int n = (2 * p + half) * 16 + (lane & 15);
        long src = (n < 512) ? ((long)k * 512 + n) : ((long)(256 + k) * 512 + (n - 512));
        w1p[idx] = f2fp8(load_f(W1, src, isf));
    } else {                               // bias conv + dtype flags (1 block, 512 threads)
        int is32 = detect_is32_w(pairs);
        int isf  = detect_isf_w((const unsigned short*)objf);
        b1f[t] = load_f(b1, t, isf);
        b2f[t] = load_f(b2, t, isf);
        if (t == 0) { flag[0] = is32; flag[1] = isf; }   // zeroed flag[2] stays (K1 zero blocks)
    }
}

// ---------- K2: gemm1 (blocks first) + edge pass + W2cat pack ----------
// gemm1: P[50k][1024] fp8 = cvt_fp8(objf) @ W1cat[256][1024]; objf converted during staging.
// edge pass: atomic max/count + slot records {partner<<1|role, exp(conf)}.
// W2cat pack, fp8, [K=1024][N=256], K-concat.
#define G1_BLK 1564                        // 2 * ceil(50000/64)
#define E_BLK 391                          // ceil(200000/512)
#define W2_BLK 512
__global__ __launch_bounds__(512, 4) void gemm1_plus(
    const void* __restrict__ objf, const int* __restrict__ pairs, const void* __restrict__ conf,
    const void* __restrict__ W2,
    const unsigned char* __restrict__ w1p, unsigned char* __restrict__ w2p,
    unsigned char* __restrict__ P,
    float* __restrict__ mbuf, int* __restrict__ count, int* __restrict__ flag,
    int2* __restrict__ inc2, int4* __restrict__ ovf)
{
    const int tid = threadIdx.x;
    if (blockIdx.x >= G1_BLK) {
        int bb = blockIdx.x - G1_BLK;
        if (bb < E_BLK) {                  // edge pass
            int is32 = detect_is32_w(pairs);
            int isf  = detect_isf_w((const unsigned short*)objf);
            int i = bb * 512 + tid;
            if (i >= N_EDGES) return;
            int s = get_pair(pairs, i, 0, is32);
            int o = get_pair(pairs, i, 1, is32);
            float c = load_f(conf, i, isf);
            c = fminf(fmaxf(c, -80.f), 80.f);     // keep exp finite; identity for |c|<=80
            int cb = __float_as_int(c);
            int eb = __float_as_int(__expf(c));   // records carry exp(conf); w = expc*exp(-mm)
            // mbuf zeroed in K1; mbuf = max(0, max conf) — shift point arbitrary, rescaled
            // exactly by S = exp(mbuf - max(mbuf,10)) in the gemm2 epilogue.
            atomicMax((int*)&mbuf[s], cb);
            atomicMax((int*)&mbuf[o], cb);
            int idx_s = atomicAdd(&count[s], 1);
            int rec_s = (o << 1) | 0;             // s is SUB of edge i
            if (idx_s < S_SLOTS) inc2[(long)s * S_SLOTS + idx_s] = make_int2(rec_s, eb);
            else { int oi = atomicAdd(&flag[2], 1); if (oi < OVF_CAP) ovf[oi] = make_int4(s, rec_s, eb, 0); }
            int idx_o = atomicAdd(&count[o], 1);
            int rec_o = (s << 1) | 1;             // o is OBJ of edge i
            if (idx_o < S_SLOTS) inc2[(long)o * S_SLOTS + idx_o] = make_int2(rec_o, eb);
            else { int oi = atomicAdd(&flag[2], 1); if (oi < OVF_CAP) ovf[oi] = make_int4(o, rec_o, eb, 0); }
        } else {                           // W2cat pack
            int isf = detect_isf_w((const unsigned short*)objf);
            int idx = (bb - E_BLK) * 512 + tid;   // 0..262143
            int j = idx & 7, half = (idx >> 3) & 1, lane = (idx >> 4) & 63;
            int p = (idx >> 10) & 7, tk = idx >> 13;
            int k = tk * 32 + (lane >> 4) * 8 + j;
            int n = (2 * p + half) * 16 + (lane & 15);
            long src = (k < 512) ? ((long)k * 512 + n) : ((long)(k - 512) * 512 + 256 + n);
            w2p[idx] = f2fp8(load_f(W2, src, isf));
        }
        return;
    }

    // ---- gemm1 body ----
    extern __shared__ char smem[];
    unsigned char* sA = (unsigned char*)smem;    // frag: 16KB; epi: 64x528 = 33792

    const int isf = detect_isf_w((const unsigned short*)objf);
    const int wave = tid >> 6;
    const int lane = tid & 63;
    const int l15  = lane & 15;
    const int lq   = lane >> 4;
    const int mb   = blockIdx.x >> 1;
    const int nh   = blockIdx.x & 1;
    const long bs  = (long)mb * 64;

    // stage A: 64 rows x 32 k-octets = 2048 uint2; 4 per thread, cvt->fp8, frag-major dest
    #pragma unroll
    for (int it = 0; it < 4; ++it) {
        int q   = it * 512 + tid;
        int m15 = q & 15;
        int mtp = (q >> 4) & 1;
        int h   = (q >> 5) & 1;
        int lqk = (q >> 6) & 3;
        int tk  = (q >> 8) & 7;
        int m   = (h * 2 + mtp) * 16 + m15;
        long node = bs + m; if (node >= O_NODES) node = O_NODES - 1;
        long f4 = node * 64 + tk * 8 + lqk * 2;   // float4/ushort4 index (4 values each)
        uint2 v;
        if (isf) {
            float4 a = ((const float4*)objf)[f4];
            float4 c = ((const float4*)objf)[f4 + 1];
            v.x = pack4_fp8(a.x, a.y, a.z, a.w);
            v.y = pack4_fp8(c.x, c.y, c.z, c.w);
        } else {
            ushort4 a = ((const ushort4*)objf)[f4];
            ushort4 c = ((const ushort4*)objf)[f4 + 1];
            v.x = pack4_fp8(bf2f(a.x), bf2f(a.y), bf2f(a.z), bf2f(a.w));
            v.y = pack4_fp8(bf2f(c.x), bf2f(c.y), bf2f(c.z), bf2f(c.w));
        }
        *(uint2*)(sA + h * 8192 + (tk * 64 + lqk * 16 + m15) * 16 + mtp * 8) = v;
    }
    __syncthreads();

    f32x4 acc[4][4];
    #pragma unroll
    for (int mt = 0; mt < 4; ++mt)
        #pragma unroll
        for (int nt = 0; nt < 4; ++nt)
            acc[mt][nt] = (f32x4){0.f, 0.f, 0.f, 0.f};

    {
        const ulonglong2* bq = (const ulonglong2*)w1p;
        const int pbase = nh * 16 + wave * 2;
        #pragma unroll 2
        for (int tk = 0; tk < 8; ++tk) {
            ulonglong2 av01 = *(const ulonglong2*)(sA + tk * 1024 + lane * 16);
            ulonglong2 av23 = *(const ulonglong2*)(sA + 8192 + tk * 1024 + lane * 16);
            ulonglong2 b01  = bq[(tk * 32 + pbase) * 64 + lane];
            ulonglong2 b23  = bq[(tk * 32 + pbase + 1) * 64 + lane];
            long a0 = (long)av01.x, a1 = (long)av01.y;
            long a2 = (long)av23.x, a3 = (long)av23.y;
            acc[0][0] = mfma_fp8(a0, (long)b01.x, acc[0][0]);
            acc[1][0] = mfma_fp8(a1, (long)b01.x, acc[1][0]);
            acc[2][0] = mfma_fp8(a2, (long)b01.x, acc[2][0]);
            acc[3][0] = mfma_fp8(a3, (long)b01.x, acc[3][0]);
            acc[0][1] = mfma_fp8(a0, (long)b01.y, acc[0][1]);
            acc[1][1] = mfma_fp8(a1, (long)b01.y, acc[1][1]);
            acc[2][1] = mfma_fp8(a2, (long)b01.y, acc[2][1]);
            acc[3][1] = mfma_fp8(a3, (long)b01.y, acc[3][1]);
            acc[0][2] = mfma_fp8(a0, (long)b23.x, acc[0][2]);
            acc[1][2] = mfma_fp8(a1, (long)b23.x, acc[1][2]);
            acc[2][2] = mfma_fp8(a2, (long)b23.x, acc[2][2]);
            acc[3][2] = mfma_fp8(a3, (long)b23.x, acc[3][2]);
            acc[0][3] = mfma_fp8(a0, (long)b23.y, acc[0][3]);
            acc[1][3] = mfma_fp8(a1, (long)b23.y, acc[1][3]);
            acc[2][3] = mfma_fp8(a2, (long)b23.y, acc[2][3]);
            acc[3][3] = mfma_fp8(a3, (long)b23.y, acc[3][3]);
        }
    }
    __syncthreads();

    // fp8 row-major (stride 528) -> coalesced stream into P
    #pragma unroll
    for (int nt = 0; nt < 4; ++nt) {
        int c = wave * 64 + nt * 16 + l15;
        #pragma unroll
        for (int mt = 0; mt < 4; ++mt) {
            #pragma unroll
            for (int r = 0; r < 4; ++r) {
                sA[(mt * 16 + lq * 4 + r) * 528 + c] = f2fp8(acc[mt][nt][r]);
            }
        }
    }
    __syncthreads();
    #pragma unroll
    for (int it = 0; it < 4; ++it) {
        int idx = it * 512 + tid;
        int row = idx >> 5;
        int ch  = idx & 31;
        if (bs + row < O_NODES) {
            uint4 v = *(const uint4*)(sA + row * 528 + ch * 16);
            ((uint4*)P)[(bs + row) * 64 + nh * 32 + ch] = v;
        }
    }
}

// ---------- per-node weighted-h accumulation (round-5 structure, 4 nodes/slice) ----------
// 2 waves/node-slice (256-dim halves), 4 nodes serial per wave.
// Records read via wave-uniform SCALAR loads (static slot addresses) — no shfl/DS ops.
__global__ __launch_bounds__(256) void node_accum(
    const unsigned* __restrict__ Pu,     // P as uints, row = 256 uints
    const int2* __restrict__ inc2,       // [50000][32] {partner<<1|role, exp(conf) bits}
    const int* __restrict__ count,
    const float* __restrict__ mbuf,
    const int* __restrict__ flag,        // flag[2] = overflow count
    const int4* __restrict__ ovf,
    const float4* __restrict__ b1f4,
    unsigned* __restrict__ Hcat_u,       // row = 256 uints: [Hs 128 | Ho 128]
    float* __restrict__ ws_s, float* __restrict__ ws_o)
{
    const int lane = threadIdx.x & 63;
    const int hw   = (threadIdx.x >> 6) & 1;             // 256-dim half owned by this wave
    const int nbase = __builtin_amdgcn_readfirstlane(
        (blockIdx.x * 2 + (threadIdx.x >> 7)) * 4);      // 6250 blocks * 2 slices * 4 = 50000
    const int col  = hw * 64 + lane;

    float4 bqv = b1f4[col];
    f32x4 b1v = {bqv.x, bqv.y, bqv.z, bqv.w};

    // prefetch node 0 self rows
    unsigned st = Pu[(long)nbase * 256 + col];
    unsigned sb = Pu[(long)nbase * 256 + 128 + col];

    #pragma unroll 1
    for (int t = 0; t < 4; ++t) {
        const int n = nbase + t;
        const int deg = count[n];                         // scalar load
        const float mm = mbuf[n];                         // scalar load
        const float emm = __expf(-mm);
        const int2* srec = inc2 + (long)n * S_SLOTS;
        // batch-0 records: scalar dwordx4 loads (slots always allocated; unused => ignored)
        int4 r0 = *(const int4*)(srec);
        int4 r1 = *(const int4*)(srec + 2);
        int4 r2 = *(const int4*)(srec + 4);
        int4 r3 = *(const int4*)(srec + 6);
        // prefetch next node's self rows
        unsigned stn = 0, sbn = 0;
        if (t < 3) {
            stn = Pu[(long)(n + 1) * 256 + col];
            sbn = Pu[(long)(n + 1) * 256 + 128 + col];
        }
        f32x4 ots = unpack4_fp8(st), obs = unpack4_fp8(sb);
        f32x4 otb, obb;
        #pragma unroll
        for (int j = 0; j < 4; ++j) { otb[j] = ots[j] + b1v[j]; obb[j] = obs[j] + b1v[j]; }

        f32x4 accS = {0.f, 0.f, 0.f, 0.f}, accO = {0.f, 0.f, 0.f, 0.f};
        float wS = 0.f, wO = 0.f;

        auto ACC = [&](int rx, int ry, unsigned pv) {
            float wk = __int_as_float(ry) * emm;
            f32x4 pp = unpack4_fp8(pv);
            if (rx & 1) {        // wave-uniform: n is OBJ of this edge
                wO += wk;
                #pragma unroll
                for (int j = 0; j < 4; ++j) accO[j] += wk * fmaxf(obb[j] + pp[j], 0.f);
            } else {             // n is SUB
                wS += wk;
                #pragma unroll
                for (int j = 0; j < 4; ++j) accS[j] += wk * fmaxf(otb[j] + pp[j], 0.f);
            }
        };

        const int nb = deg < S_SLOTS ? deg : S_SLOTS;
        for (int i = 0; i < nb; i += 8) {
            int kb = nb - i; if (kb > 8) kb = 8;
            if (i) {
                r0 = *(const int4*)(srec + i);
                r1 = *(const int4*)(srec + i + 2);
                r2 = *(const int4*)(srec + i + 4);
                r3 = *(const int4*)(srec + i + 6);
            }
            if (kb == 8) {       // fast path: 8 partner loads in flight, no predication
                unsigned p0 = Pu[(long)(r0.x >> 1) * 256 + ((r0.x & 1) ? 0 : 128) + col];
                unsigned p1 = Pu[(long)(r0.z >> 1) * 256 + ((r0.z & 1) ? 0 : 128) + col];
                unsigned p2 = Pu[(long)(r1.x >> 1) * 256 + ((r1.x & 1) ? 0 : 128) + col];
                unsigned p3 = Pu[(long)(r1.z >> 1) * 256 + ((r1.z & 1) ? 0 : 128) + col];
                unsigned p4 = Pu[(long)(r2.x >> 1) * 256 + ((r2.x & 1) ? 0 : 128) + col];
                unsigned p5 = Pu[(long)(r2.z >> 1) * 256 + ((r2.z & 1) ? 0 : 128) + col];
                unsigned p6 = Pu[(long)(r3.x >> 1) * 256 + ((r3.x & 1) ? 0 : 128) + col];
                unsigned p7 = Pu[(long)(r3.z >> 1) * 256 + ((r3.z & 1) ? 0 : 128) + col];
                ACC(r0.x, r0.y, p0); ACC(r0.z, r0.w, p1);
                ACC(r1.x, r1.y, p2); ACC(r1.z, r1.w, p3);
                ACC(r2.x, r2.y, p4); ACC(r2.z, r2.w, p5);
                ACC(r3.x, r3.y, p6); ACC(r3.z, r3.w, p7);
            } else {             // tail: <=7 incidences, simple scalar-record loop
                for (int k = 0; k < kb; ++k) {
                    int2 rr = srec[i + k];
                    unsigned pv = Pu[(long)(rr.x >> 1) * 256 + ((rr.x & 1) ? 0 : 128) + col];
                    ACC(rr.x, rr.y, pv);
                }
            }
        }
        if (deg > S_SLOTS) {     // rare overflow: walk the global overflow list
            int no = flag[2]; if (no > OVF_CAP) no = OVF_CAP;
            for (int tt = 0; tt < no; ++tt) {
                int4 o = ovf[tt];
                if (o.x == n) {
                    unsigned pv = Pu[(long)(o.y >> 1) * 256 + ((o.y & 1) ? 0 : 128) + col];
                    ACC(o.y, o.z, pv);
                }
            }
        }
        long hrow = (long)n * 256;
        Hcat_u[hrow + col]       = pack4_fp8(accS[0], accS[1], accS[2], accS[3]);
        Hcat_u[hrow + 128 + col] = pack4_fp8(accO[0], accO[1], accO[2], accO[3]);
        if (hw == 0 && lane == 0) { ws_s[n] = wS; ws_o[n] = wO; }
        st = stn; sb = sbn;
    }
}

// ---------- node-level GEMM2 + fused finalize ----------
__global__ __launch_bounds__(512, 4) void gemm2_node(
    const unsigned* __restrict__ Hcat,
    const unsigned char* __restrict__ w2p,
    const float* __restrict__ mbuf,
    const float* __restrict__ ws_s, const float* __restrict__ ws_o,
    const void* __restrict__ objf, const float* __restrict__ b2f,
    void* __restrict__ out, const int* __restrict__ flag)
{
    extern __shared__ char smem[];
    unsigned char* sA = (unsigned char*)smem;     // 32KB frags
    float* sS    = (float*)(smem + 32768);        // [64] each
    float* sSelf = sS + 64;
    float* sInv  = sS + 128;
    float* sWs   = sS + 192;
    float* sWo   = sS + 256;

    const int tid  = threadIdx.x;
    const int wave = tid >> 6;
    const int lane = tid & 63;
    const int l15  = lane & 15;
    const int lq   = lane >> 4;
    const long bs  = (long)blockIdx.x * 64;
    const int isf  = flag[1];

    if (tid < 64) {
        long node = bs + tid; if (node >= O_NODES) node = O_NODES - 1;
        float mm = mbuf[node];
        float mn = fmaxf(mm, 10.0f);
        float S     = __expf(mm - mn);
        float selfw = __expf(10.0f - mn);
        float wss = ws_s[node], wso = ws_o[node];
        sS[tid] = S; sSelf[tid] = selfw; sWs[tid] = wss; sWo[tid] = wso;
        sInv[tid] = 1.0f / (S * (wss + wso) + selfw);
    }

    f32x4 acc[4][2];
    #pragma unroll
    for (int mt = 0; mt < 4; ++mt)
        #pragma unroll
        for (int nt = 0; nt < 2; ++nt)
            acc[mt][nt] = (f32x4){0.f, 0.f, 0.f, 0.f};

    const ulonglong2* bq = (const ulonglong2*)w2p;
    #pragma unroll
    for (int kh = 0; kh < 2; ++kh) {
        #pragma unroll
        for (int it = 0; it < 8; ++it) {
            int q   = it * 512 + tid;
            int m15 = q & 15;
            int mtp = (q >> 4) & 1;
            int h   = (q >> 5) & 1;
            int lqk = (q >> 6) & 3;
            int tk  = (q >> 8) & 15;
            int m   = (h * 2 + mtp) * 16 + m15;
            long node = bs + m; if (node >= O_NODES) node = O_NODES - 1;
            uint2 v = *(const uint2*)(Hcat + node * 256 + kh * 128 + tk * 8 + lqk * 2);
            *(uint2*)(sA + h * 16384 + (tk * 64 + lqk * 16 + m15) * 16 + mtp * 8) = v;
        }
        __syncthreads();
        #pragma unroll 2
        for (int tk = 0; tk < 16; ++tk) {
            int kt = kh * 16 + tk;
            ulonglong2 av01 = *(const ulonglong2*)(sA + tk * 1024 + lane * 16);
            ulonglong2 av23 = *(const ulonglong2*)(sA + 16384 + tk * 1024 + lane * 16);
            ulonglong2 b    = bq[(kt * 8 + wave) * 64 + lane];
            long a0 = (long)av01.x, a1 = (long)av01.y;
            long a2 = (long)av23.x, a3 = (long)av23.y;
            acc[0][0] = mfma_fp8(a0, (long)b.x, acc[0][0]);
            acc[1][0] = mfma_fp8(a1, (long)b.x, acc[1][0]);
            acc[2][0] = mfma_fp8(a2, (long)b.x, acc[2][0]);
            acc[3][0] = mfma_fp8(a3, (long)b.x, acc[3][0]);
            acc[0][1] = mfma_fp8(a0, (long)b.y, acc[0][1]);
            acc[1][1] = mfma_fp8(a1, (long)b.y, acc[1][1]);
            acc[2][1] = mfma_fp8(a2, (long)b.y, acc[2][1]);
            acc[3][1] = mfma_fp8(a3, (long)b.y, acc[3][1]);
        }
        __syncthreads();
    }

    // fused finalize epilogue
    #pragma unroll
    for (int nt = 0; nt < 2; ++nt) {
        int c = wave * 32 + nt * 16 + l15;
        float b2c = b2f[c];
        float b2d = b2f[256 + c];
        #pragma unroll
        for (int mt = 0; mt < 4; ++mt) {
            #pragma unroll
            for (int r = 0; r < 4; ++r) {
                int row = mt * 16 + lq * 4 + r;
                long node = bs + row;
                if (node < O_NODES) {
                    float o = load_f(objf, node * 256 + c, isf);
                    float val = (sS[row] * (acc[mt][nt][r] + sWs[row] * b2c + sWo[row] * b2d)
                                 + sSelf[row] * o) * sInv[row];
                    if (isf) ((float*)out)[node * 256 + c] = val;
                    else     ((unsigned short*)out)[node * 256 + c] = f2bf(val);
                }
            }
        }
    }
}

extern "C" void kernel_launch(void* const* d_in, const int* in_sizes, int n_in,
                              void* d_out, int out_size, void* d_ws, size_t ws_size,
                              hipStream_t stream) {
    const void* objf  = d_in[0];
    const int*  pairs = (const int*)d_in[1];
    const void* conf  = d_in[2];
    const void* W1    = d_in[3];
    const void* b1    = d_in[4];
    const void* W2    = d_in[5];
    const void* b2    = d_in[6];

    char* ws = (char*)d_ws;
    // layout (bytes):
    //   0         count   200000
    //   200000    mbuf    200000
    //   400000    flag    64       (flag[2] = overflow counter)  [0..400064 zeroed by K1]
    //   400064    ovf     65536    (int4 x 4096)
    //   465600    w1p     262144
    //   727744    w2p     262144
    //   989888    ws_s    200000
    //   1189888   ws_o    200000
    //   1389888   b1f     2048
    //   1391936   b2f     2048
    //   1393984   inc2    12800000 (int2 slots [50000][32])
    //   14193984  P       51200000 (fp8 [50k][1024])
    //   65393984  Hcat    51200000
    //   end = 116,593,984  (< 118,124,352 proven available)
    int*   count   = (int*)  ws;
    float* mbuf    = (float*)(ws + 200000);
    int*   flag    = (int*)  (ws + 400000);
    int4*  ovf     = (int4*) (ws + 400064);
    unsigned char* w1p = (unsigned char*)(ws + 465600);
    unsigned char* w2p = (unsigned char*)(ws + 727744);
    float* wss     = (float*)(ws + 989888);
    float* wso     = (float*)(ws + 1189888);
    float* b1f     = (float*)(ws + 1389888);
    float* b2f     = (float*)(ws + 1391936);
    int2*  inc2    = (int2*) (ws + 1393984);
    unsigned char* P     = (unsigned char*)(ws + 14193984);
    unsigned char* Hcat  = (unsigned char*)(ws + 65393984);

    // K1: zero + W1 pack + bias conv + flags (no deps)
    setup1<<<Z_BLK + W1_BLK + 1, 512, 0, stream>>>(
        objf, pairs, W1, b1, b2, w1p, b1f, b2f, ws, flag);

    // K2: gemm1 (first 1564 blocks) + edge pass + W2 pack (overlapped)
    gemm1_plus<<<G1_BLK + E_BLK + W2_BLK, 512, 33792, stream>>>(
        objf, pairs, conf, W2, w1p, w2p, P, mbuf, count, flag, inc2, ovf);

    // K3: per-node weighted-h accumulation
    node_accum<<<O_NODES / 8, 256, 0, stream>>>(
        (const unsigned*)P, inc2, count, mbuf, flag, ovf, (const float4*)b1f,
        (unsigned*)Hcat, wss, wso);

    // K4: gemm2 + fused finalize
    gemm2_node<<<(O_NODES + 63) / 64, 512, 34048, stream>>>(
        (const unsigned*)Hcat, w2p, mbuf, wss, wso, objf, b2f, d_out, flag);
}